// Round 1
// baseline (317.204 us; speedup 1.0000x reference)
//
#include <hip/hip_runtime.h>
#include <stdint.h>

// Problem constants (fixed by reference setup_inputs)
constexpr int N = 65536, K = 512, F = 512;
constexpr float ASCALE = 127.0f / 3.0f;   // activation scale (fixed bound 3.0)

typedef short frag8 __attribute__((ext_vector_type(8)));   // 8 bf16 = 4 VGPRs
typedef float floatx4 __attribute__((ext_vector_type(4))); // MFMA C/D

// round-half-even, clip to [-127,127], truncate fp32->bf16 (exact for ints <= 127)
__device__ __forceinline__ unsigned short quant_bf16(float v, float s) {
    float q = rintf(v * s);
    q = fminf(fmaxf(q, -127.0f), 127.0f);
    union { float f; unsigned int u; } cvt; cvt.f = q;
    return (unsigned short)(cvt.u >> 16);
}

// --- Phase 1: per-output-channel weight quant -> wT[f][k] (bf16), dscale[f] ---
// grid 64 x 64 threads; block b owns columns f in [b*8, b*8+8); 8 lanes per f
// partition K into 8 chunks of 64.
__global__ void quant_w_kernel(const float* __restrict__ kern,
                               unsigned short* __restrict__ wT,
                               float* __restrict__ dscale) {
    int t = threadIdx.x;         // 0..63
    int b = blockIdx.x;          // 0..63
    int fl = t & 7;              // f lane
    int kp = t >> 3;             // k partition 0..7
    int f = b * 8 + fl;
    int kbase = kp * 64;

    float mx = 0.0f;
    #pragma unroll 8
    for (int k = 0; k < 64; ++k)
        mx = fmaxf(mx, fabsf(kern[(size_t)(kbase + k) * F + f]));
    // reduce across the 8 k-partitions (t bits 3..5)
    #pragma unroll
    for (int d = 8; d < 64; d <<= 1)
        mx = fmaxf(mx, __shfl_xor(mx, d, 64));

    float m = fmaxf(mx, 1e-7f);
    float wsc = 127.0f / m;
    if (kp == 0) dscale[f] = 3.0f * m / 16129.0f;  // 1/(a_scale*w_scale)

    // quantize this partition's rows of column f, write contiguous to wT[f][.]
    for (int k0 = 0; k0 < 64; k0 += 8) {
        unsigned short q[8];
        #pragma unroll
        for (int j = 0; j < 8; ++j)
            q[j] = quant_bf16(kern[(size_t)(kbase + k0 + j) * F + f], wsc);
        uint4 pack;
        pack.x = (unsigned int)q[0] | ((unsigned int)q[1] << 16);
        pack.y = (unsigned int)q[2] | ((unsigned int)q[3] << 16);
        pack.z = (unsigned int)q[4] | ((unsigned int)q[5] << 16);
        pack.w = (unsigned int)q[6] | ((unsigned int)q[7] << 16);
        *(uint4*)&wT[(size_t)f * K + kbase + k0] = pack;
    }
}

// --- Phase 2: fused quant-x + int-exact bf16 MFMA GEMM + dequant + bias ---
// Block: 512 threads (8 waves). BM=64, BN=F=512, BK=32. Wave w owns cols
// [w*64, w*64+64) over all 64 rows: 4x4 tiles of 16x16x32 bf16 MFMA.
__global__ __launch_bounds__(512, 4)
void gemm_kernel(const float* __restrict__ x,
                 const unsigned short* __restrict__ wT,
                 const float* __restrict__ dscale,
                 const float* __restrict__ bias,
                 float* __restrict__ out) {
    constexpr int BM = 64, BK = 32;
    constexpr int LDA = 40, LDB = 40;   // +8 bf16 pad: 2-way banks (free)
    __shared__ unsigned short As[BM * LDA];   // As[m][k]
    __shared__ unsigned short Bs[F * LDB];    // Bs[n][k]  (w transposed)

    int t = threadIdx.x;
    int blk = blockIdx.x;
    int lane = t & 63;
    int wave = t >> 6;           // 0..7
    int m16 = lane & 15;
    int quad = lane >> 4;

    floatx4 acc[4][4];
    #pragma unroll
    for (int i = 0; i < 4; ++i)
        #pragma unroll
        for (int j = 0; j < 4; ++j)
            acc[i][j] = (floatx4){0.f, 0.f, 0.f, 0.f};

    // A staging: thread -> (row = t/8, 4 cols at (t%8)*4), float4 coalesced
    int arow = t >> 3;
    int acol = (t & 7) * 4;
    const float* xp = x + (size_t)(blk * BM + arow) * K + acol;
    // B staging: thread -> (n = p*128 + t/4, 16B chunk (t%4)), 4 passes
    int bn = t >> 2;
    int bc = t & 3;

    for (int kt = 0; kt < K / BK; ++kt) {
        int k0 = kt * BK;
        // quantize x tile -> As (bf16)
        float4 v = *(const float4*)(xp + k0);
        ushort4 qa;
        qa.x = quant_bf16(v.x, ASCALE);
        qa.y = quant_bf16(v.y, ASCALE);
        qa.z = quant_bf16(v.z, ASCALE);
        qa.w = quant_bf16(v.w, ASCALE);
        *(ushort4*)&As[arow * LDA + acol] = qa;
        // stage w tile -> Bs
        #pragma unroll
        for (int p = 0; p < 4; ++p) {
            int n = p * 128 + bn;
            uint4 d = *(const uint4*)(wT + (size_t)n * K + k0 + bc * 8);
            *(uint4*)&Bs[n * LDB + bc * 8] = d;
        }
        __syncthreads();

        // A frags: lane holds A[m16 + mt*16][quad*8 .. +8]
        frag8 af[4];
        #pragma unroll
        for (int mt = 0; mt < 4; ++mt)
            af[mt] = *(const frag8*)&As[(mt * 16 + m16) * LDA + quad * 8];
        #pragma unroll
        for (int nt = 0; nt < 4; ++nt) {
            frag8 bf = *(const frag8*)&Bs[(wave * 64 + nt * 16 + m16) * LDB + quad * 8];
            #pragma unroll
            for (int mt = 0; mt < 4; ++mt)
                acc[mt][nt] = __builtin_amdgcn_mfma_f32_16x16x32_bf16(
                    af[mt], bf, acc[mt][nt], 0, 0, 0);
        }
        __syncthreads();
    }

    // epilogue: C layout col=lane&15, row=quad*4+reg (m89/m91-verified)
    #pragma unroll
    for (int nt = 0; nt < 4; ++nt) {
        int col = wave * 64 + nt * 16 + m16;
        float ds = dscale[col];
        float bv = bias[col];
        #pragma unroll
        for (int mt = 0; mt < 4; ++mt) {
            int row = blk * BM + mt * 16 + quad * 4;
            #pragma unroll
            for (int r = 0; r < 4; ++r)
                out[(size_t)(row + r) * F + col] = acc[mt][nt][r] * ds + bv;
        }
    }
}

extern "C" void kernel_launch(void* const* d_in, const int* in_sizes, int n_in,
                              void* d_out, int out_size, void* d_ws, size_t ws_size,
                              hipStream_t stream) {
    const float* x    = (const float*)d_in[0];
    const float* kern = (const float*)d_in[1];
    const float* bias = (const float*)d_in[2];
    float* out = (float*)d_out;

    unsigned short* wT = (unsigned short*)d_ws;                       // 512*512 bf16 = 512 KB
    float* dscale = (float*)((char*)d_ws + (size_t)K * F * sizeof(unsigned short));

    quant_w_kernel<<<64, 64, 0, stream>>>(kern, wT, dscale);
    gemm_kernel<<<N / 64, 512, 0, stream>>>(x, wT, dscale, bias, out);
}